// Round 10
// baseline (153.180 us; speedup 1.0000x reference)
//
#include <hip/hip_runtime.h>

#define D_MODEL 2048
#define N_EXP 8
#define TOPK 2
#define TPB 64                // tokens per block/group
#define SPLIT 4               // k-split factor
#define KQ (D_MODEL / SPLIT)  // 512 floats per quarter
#define TILE 64               // floats per tile per row
#define NT (KQ / TILE)        // 8 tiles
#define TSTR 65               // transposed LDS stride: [k][token], +1 pad
#define OSTR 68               // overlay floats per token

// Single fused launch. Grid = 256 token-groups x 4 k-quarters = 1024 blocks
// (4/CU, 8 waves/SIMD). Gate identical to R9 (transposed-LDS, SGPR W operands,
// in-lane accumulation). Fusion: after writing its quarter's partial logits,
// each block tickets done[tb]; the LAST block of a group finalizes its 64
// tokens (fixed-order quarter sum -> deterministic), writes outputs, and
// accumulates a histogram into ghist; a second ticket (gdone) makes the last
// group compute aux_loss/load from ghist (atomic reads, integer counts).
__global__ __launch_bounds__(512, 8) void gate_fused_kernel(
    const float* __restrict__ H, const float* __restrict__ W,
    float* __restrict__ part_ws, unsigned int* __restrict__ done,
    unsigned int* __restrict__ ghist, unsigned int* __restrict__ gdone,
    float* __restrict__ out_idx, float* __restrict__ out_prob,
    float* __restrict__ out_aux, float* __restrict__ out_load,
    int n_tokens, int ngroups)
{
    __shared__ float lbuf[2][TILE][TSTR];   // 33280 B
    __shared__ unsigned int lhist[N_EXP];
    __shared__ int lastflag;

    const int tid = threadIdx.x;
    const int lane = tid & 63;
    const int w = tid >> 6;               // 0..7
    const int tb = blockIdx.x >> 2;
    const int q = blockIdx.x & 3;         // k-quarter
    const int t0 = tb * TPB;
    const int wc = __builtin_amdgcn_readfirstlane(w);

    if (tid < N_EXP) lhist[tid] = 0u;

    // Staging coords: thread stages row srow, float4 slots scol and scol+8.
    const int srow = tid >> 3;            // 0..63 (token row)
    const int scol = tid & 7;
    const bool svalid = (t0 + srow) < n_tokens;
    const float4* hrow = reinterpret_cast<const float4*>(H)
                         + (size_t)(t0 + srow) * (D_MODEL / 4) + q * (KQ / 4);
    const float* Wq = W + q * KQ;         // expert stride D_MODEL
    const float4 fz = make_float4(0.f, 0.f, 0.f, 0.f);

    float acc[N_EXP];
#pragma unroll
    for (int e = 0; e < N_EXP; ++e) acc[e] = 0.f;

    // Prologue: stage tile 0 (transposed scatter: 4 b32 per float4).
    {
        float4 r0 = svalid ? hrow[scol] : fz;
        float4 r1 = svalid ? hrow[scol + 8] : fz;
        const float* p0 = reinterpret_cast<const float*>(&r0);
        const float* p1 = reinterpret_cast<const float*>(&r1);
#pragma unroll
        for (int jj = 0; jj < 4; ++jj) {
            lbuf[0][4 * scol + jj][srow] = p0[jj];
            lbuf[0][4 * (scol + 8) + jj][srow] = p1[jj];
        }
    }
    __syncthreads();

#pragma unroll
    for (int j = 0; j < NT; ++j) {
        const int b = j & 1;
        const bool pf = (j + 1 < NT);
        float4 r0 = fz, r1 = fz;
        if (pf && svalid) {               // issue next-tile loads early
            r0 = hrow[(j + 1) * 16 + scol];
            r1 = hrow[(j + 1) * 16 + scol + 8];
        }

        // Compute tile j: token = lane, k = wc*8 + i (conflict-free b32 reads).
        float x[8];
#pragma unroll
        for (int i = 0; i < 8; ++i) x[i] = lbuf[b][wc * 8 + i][lane];
#pragma unroll
        for (int e = 0; e < N_EXP; ++e) {
            float a = acc[e];
#pragma unroll
            for (int i = 0; i < 8; ++i)
                a = fmaf(x[i], Wq[e * D_MODEL + j * TILE + wc * 8 + i], a);  // scalar
            acc[e] = a;
        }

        if (pf) {
            const float* p0 = reinterpret_cast<const float*>(&r0);
            const float* p1 = reinterpret_cast<const float*>(&r1);
#pragma unroll
            for (int jj = 0; jj < 4; ++jj) {
                lbuf[b ^ 1][4 * scol + jj][srow] = p0[jj];
                lbuf[b ^ 1][4 * (scol + 8) + jj][srow] = p1[jj];
            }
        }
        __syncthreads();
    }

    // Partials -> LDS overlay (free after the last barrier).
    float* part = &lbuf[0][0][0];
    {
        float* dst = part + lane * OSTR + wc * 8;
        *reinterpret_cast<float4*>(dst) = make_float4(acc[0], acc[1], acc[2], acc[3]);
        *reinterpret_cast<float4*>(dst + 4) = make_float4(acc[4], acc[5], acc[6], acc[7]);
    }
    __syncthreads();

    // Wave 0: fixed-order 8-chunk sum -> 8 quarter-logits -> part_ws[tb][q][tok][e].
    if (w == 0 && (t0 + lane) < n_tokens) {
        const float* src = part + lane * OSTR;
        float4 s0 = *reinterpret_cast<const float4*>(src);
        float4 s1 = *reinterpret_cast<const float4*>(src + 4);
        float lg[N_EXP] = {s0.x, s0.y, s0.z, s0.w, s1.x, s1.y, s1.z, s1.w};
#pragma unroll
        for (int c = 1; c < 8; ++c) {
            float4 c0 = *reinterpret_cast<const float4*>(src + c * 8);
            float4 c1 = *reinterpret_cast<const float4*>(src + c * 8 + 4);
            lg[0] += c0.x; lg[1] += c0.y; lg[2] += c0.z; lg[3] += c0.w;
            lg[4] += c1.x; lg[5] += c1.y; lg[6] += c1.z; lg[7] += c1.w;
        }
        float* dst = part_ws + ((size_t)(tb * SPLIT + q) * TPB + lane) * 8;
        *reinterpret_cast<float4*>(dst) = make_float4(lg[0], lg[1], lg[2], lg[3]);
        *reinterpret_cast<float4*>(dst + 4) = make_float4(lg[4], lg[5], lg[6], lg[7]);
    }

    __syncthreads();   // barrier drains the part_ws writes (vmcnt)

    if (tid == 0) {
        __threadfence();                          // release: flush this XCD's L2
        unsigned int old = atomicAdd(&done[tb], 1u);
        lastflag = (old == SPLIT - 1) ? 1 : 0;
    }
    __syncthreads();

    if (lastflag) {
        __threadfence();                          // acquire
        if (w == 0 && (t0 + lane) < n_tokens) {
            const int t = t0 + lane;
            const float* gbase = part_ws + (size_t)tb * SPLIT * TPB * 8;
            float lg[N_EXP] = {0.f, 0.f, 0.f, 0.f, 0.f, 0.f, 0.f, 0.f};
#pragma unroll
            for (int qq = 0; qq < SPLIT; ++qq) {  // fixed order -> deterministic
                const float4* src = reinterpret_cast<const float4*>(
                    gbase + ((size_t)qq * TPB + lane) * 8);
                const float4 a0 = src[0], a1 = src[1];
                lg[0] += a0.x; lg[1] += a0.y; lg[2] += a0.z; lg[3] += a0.w;
                lg[4] += a1.x; lg[5] += a1.y; lg[6] += a1.z; lg[7] += a1.w;
            }

            float m = lg[0];
#pragma unroll
            for (int e = 1; e < N_EXP; ++e) m = fmaxf(m, lg[e]);
            float p[N_EXP], s = 0.f;
#pragma unroll
            for (int e = 0; e < N_EXP; ++e) { p[e] = expf(lg[e] - m); s += p[e]; }
            const float inv = 1.f / s;

            float v1 = -INFINITY, v2 = -INFINITY;
            int i1 = 0, i2 = 0;
#pragma unroll
            for (int e = 0; e < N_EXP; ++e) {
                float vv = lg[e];
                if (vv > v1) { v2 = v1; i2 = i1; v1 = vv; i1 = e; }
                else if (vv > v2) { v2 = vv; i2 = e; }
            }

            *reinterpret_cast<float2*>(&out_idx[2 * t]) = make_float2((float)i1, (float)i2);
            *reinterpret_cast<float2*>(&out_prob[2 * t]) = make_float2(p[i1] * inv, p[i2] * inv);
            atomicAdd(&lhist[i1], 1u);
            atomicAdd(&lhist[i2], 1u);
        }
        __syncthreads();
        if (tid < N_EXP) atomicAdd(&ghist[tid], lhist[tid]);
        __syncthreads();   // drains the ghist atomics before the gdone ticket

        if (tid == 0) {
            unsigned int old2 = atomicAdd(gdone, 1u);
            if (old2 == (unsigned int)(ngroups - 1)) {
                // Last group: all ghist contributions are complete (each group
                // tickets gdone only after its ghist atomics drained).
                const float denom = 1.0f / (float)(n_tokens * TOPK);
                float load[N_EXP], sum = 0.f;
#pragma unroll
                for (int e = 0; e < N_EXP; ++e) {
                    unsigned int c = atomicAdd(&ghist[e], 0u);  // coherent read
                    load[e] = (float)c * denom;
                    sum += load[e];
                }
                const float mean = sum / (float)N_EXP;
                float var = 0.f;
#pragma unroll
                for (int e = 0; e < N_EXP; ++e) { float d = load[e] - mean; var += d * d; }
                var /= (float)N_EXP;
                const float cv_sq = var / (mean * mean + 1e-9f);
                out_aux[0] = 0.01f * cv_sq;
#pragma unroll
                for (int e = 0; e < N_EXP; ++e) out_load[e] = load[e];
            }
        }
    }
}

extern "C" void kernel_launch(void* const* d_in, const int* in_sizes, int n_in,
                              void* d_out, int out_size, void* d_ws, size_t ws_size,
                              hipStream_t stream)
{
    const float* H = (const float*)d_in[0];
    const float* W = (const float*)d_in[1];
    const int n_tokens = in_sizes[0] / D_MODEL;  // 16384
    const int ngroups = (n_tokens + TPB - 1) / TPB;  // 256

    float* out = (float*)d_out;
    float* out_idx = out;
    float* out_prob = out + 2 * (size_t)n_tokens;
    float* out_aux = out + 4 * (size_t)n_tokens;
    float* out_load = out + 4 * (size_t)n_tokens + 1;

    // ws layout: part_ws [ngroups*SPLIT*TPB*8 floats], then semaphores.
    float* part_ws = (float*)d_ws;
    const size_t part_bytes = (size_t)ngroups * SPLIT * TPB * 8 * sizeof(float);  // 2 MB
    unsigned int* done = (unsigned int*)((char*)d_ws + part_bytes);   // ngroups
    unsigned int* ghist = done + ngroups;                             // 8
    unsigned int* gdone = ghist + N_EXP;                              // 1

    // Zero semaphores + histogram (graph-capturable async memset).
    hipMemsetAsync(done, 0, (size_t)(ngroups + N_EXP + 1) * sizeof(unsigned int), stream);

    hipLaunchKernelGGL(gate_fused_kernel, dim3(ngroups * SPLIT), dim3(512), 0, stream,
                       H, W, part_ws, done, ghist, gdone,
                       out_idx, out_prob, out_aux, out_load, n_tokens, ngroups);
}

// Round 11
// 40.821 us; speedup vs baseline: 3.7525x; 3.7525x over previous
//
#include <hip/hip_runtime.h>

#define D_MODEL 2048
#define N_EXP 8
#define TOPK 2
#define TPB 64                // tokens per block
#define SPLIT 4               // k-split factor
#define KQ (D_MODEL / SPLIT)  // 512 floats per quarter
#define TILE 64               // floats per tile per row
#define NT (KQ / TILE)        // 8 tiles
#define OSTR 68               // overlay floats per token

// Split-K4 gate, XOR-swizzled b128 LDS. Grid = 256 token-groups x 4 quarters
// = 1024 blocks (4/CU, 8 waves/SIMD). LDS tile [token][slot^(token&15)] as
// float4 (32 KB, no pad): staging = 2 ds_write_b128, compute = 2 ds_read_b128
// per thread-tile -- both bank-even under the XOR swizzle (same involution on
// write and read). W operands wave-uniform -> SGPR s_loads. Accumulation
// order identical to R9 -> same numerics.
__global__ __launch_bounds__(512, 8) void gate_partial_kernel(
    const float* __restrict__ H, const float* __restrict__ W,
    float* __restrict__ part_ws, int n_tokens)
{
    __shared__ float4 lbuf[2][TPB][16];    // 32768 B -> 4 blocks/CU

    const int tid = threadIdx.x;
    const int lane = tid & 63;
    const int w = tid >> 6;               // 0..7
    const int tb = blockIdx.x >> 2;
    const int q = blockIdx.x & 3;         // k-quarter
    const int t0 = tb * TPB;
    const int wc = __builtin_amdgcn_readfirstlane(w);

    // Staging coords: thread stages row srow, float4 slots scol and scol+8.
    const int srow = tid >> 3;            // 0..63 (token row)
    const int scol = tid & 7;
    const int sw = srow & 15;             // swizzle key for this row
    const bool svalid = (t0 + srow) < n_tokens;
    const float4* hrow = reinterpret_cast<const float4*>(H)
                         + (size_t)(t0 + srow) * (D_MODEL / 4) + q * (KQ / 4);
    const float* Wq = W + q * KQ;         // expert stride D_MODEL
    const float4 fz = make_float4(0.f, 0.f, 0.f, 0.f);

    float acc[N_EXP];
#pragma unroll
    for (int e = 0; e < N_EXP; ++e) acc[e] = 0.f;

    // Prologue: stage tile 0 (swizzled b128 writes).
    {
        float4 r0 = svalid ? hrow[scol] : fz;
        float4 r1 = svalid ? hrow[scol + 8] : fz;
        lbuf[0][srow][scol ^ sw] = r0;
        lbuf[0][srow][(scol + 8) ^ sw] = r1;
    }
    __syncthreads();

#pragma unroll
    for (int j = 0; j < NT; ++j) {
        const int b = j & 1;
        const bool pf = (j + 1 < NT);
        float4 r0 = fz, r1 = fz;
        if (pf && svalid) {               // issue next-tile loads early
            r0 = hrow[(j + 1) * 16 + scol];
            r1 = hrow[(j + 1) * 16 + scol + 8];
        }

        // Compute tile j: token = lane; k-slice [wc*8, wc*8+8) = slots 2wc,2wc+1.
        const int lsw = lane & 15;
        const float4 x0 = lbuf[b][lane][(2 * wc) ^ lsw];
        const float4 x1 = lbuf[b][lane][(2 * wc + 1) ^ lsw];
        const float x[8] = {x0.x, x0.y, x0.z, x0.w, x1.x, x1.y, x1.z, x1.w};
#pragma unroll
        for (int e = 0; e < N_EXP; ++e) {
            float a = acc[e];
#pragma unroll
            for (int i = 0; i < 8; ++i)
                a = fmaf(x[i], Wq[e * D_MODEL + j * TILE + wc * 8 + i], a);  // scalar
            acc[e] = a;
        }

        if (pf) {
            lbuf[b ^ 1][srow][scol ^ sw] = r0;
            lbuf[b ^ 1][srow][(scol + 8) ^ sw] = r1;
        }
        __syncthreads();
    }

    // Partials -> LDS overlay (lbuf storage is free after the last barrier).
    float* part = reinterpret_cast<float*>(&lbuf[0][0][0]);
    {
        float* dst = part + lane * OSTR + wc * 8;
        *reinterpret_cast<float4*>(dst) = make_float4(acc[0], acc[1], acc[2], acc[3]);
        *reinterpret_cast<float4*>(dst + 4) = make_float4(acc[4], acc[5], acc[6], acc[7]);
    }
    __syncthreads();

    // Wave 0: fixed-order 8-chunk sum -> 8 quarter-logits -> part_ws[q][t][e].
    if (w == 0 && (t0 + lane) < n_tokens) {
        const float* src = part + lane * OSTR;
        float4 s0 = *reinterpret_cast<const float4*>(src);
        float4 s1 = *reinterpret_cast<const float4*>(src + 4);
        float lg[N_EXP] = {s0.x, s0.y, s0.z, s0.w, s1.x, s1.y, s1.z, s1.w};
#pragma unroll
        for (int c = 1; c < 8; ++c) {
            float4 c0 = *reinterpret_cast<const float4*>(src + c * 8);
            float4 c1 = *reinterpret_cast<const float4*>(src + c * 8 + 4);
            lg[0] += c0.x; lg[1] += c0.y; lg[2] += c0.z; lg[3] += c0.w;
            lg[4] += c1.x; lg[5] += c1.y; lg[6] += c1.z; lg[7] += c1.w;
        }
        float* dst = part_ws + ((size_t)q * n_tokens + (t0 + lane)) * 8;
        *reinterpret_cast<float4*>(dst) = make_float4(lg[0], lg[1], lg[2], lg[3]);
        *reinterpret_cast<float4*>(dst + 4) = make_float4(lg[4], lg[5], lg[6], lg[7]);
    }
}

// Merged tail: one thread per token (32 blocks x 512). Fixed-order quarter
// sum, softmax, top-2, outputs; per-block hist -> ghist atomics; last block
// (gdone ticket) computes aux_loss/load. Fence cost: 32 executions, tiny kernel.
__global__ __launch_bounds__(512) void token_finalize_kernel(
    const float* __restrict__ part_ws,
    unsigned int* __restrict__ ghist, unsigned int* __restrict__ gdone,
    float* __restrict__ out_idx, float* __restrict__ out_prob,
    float* __restrict__ out_aux, float* __restrict__ out_load,
    int n_tokens, int nblk)
{
    __shared__ unsigned int lhist[N_EXP];
    const int tid = threadIdx.x;
    if (tid < N_EXP) lhist[tid] = 0u;
    __syncthreads();

    const int t = blockIdx.x * 512 + tid;
    if (t < n_tokens) {
        float lg[N_EXP] = {0.f, 0.f, 0.f, 0.f, 0.f, 0.f, 0.f, 0.f};
#pragma unroll
        for (int qq = 0; qq < SPLIT; ++qq) {   // fixed order -> deterministic
            const float4* src = reinterpret_cast<const float4*>(
                part_ws + ((size_t)qq * n_tokens + t) * 8);
            const float4 a0 = src[0], a1 = src[1];
            lg[0] += a0.x; lg[1] += a0.y; lg[2] += a0.z; lg[3] += a0.w;
            lg[4] += a1.x; lg[5] += a1.y; lg[6] += a1.z; lg[7] += a1.w;
        }

        float m = lg[0];
#pragma unroll
        for (int e = 1; e < N_EXP; ++e) m = fmaxf(m, lg[e]);
        float p[N_EXP], s = 0.f;
#pragma unroll
        for (int e = 0; e < N_EXP; ++e) { p[e] = expf(lg[e] - m); s += p[e]; }
        const float inv = 1.f / s;

        float v1 = -INFINITY, v2 = -INFINITY;
        int i1 = 0, i2 = 0;
#pragma unroll
        for (int e = 0; e < N_EXP; ++e) {
            float vv = lg[e];
            if (vv > v1) { v2 = v1; i2 = i1; v1 = vv; i1 = e; }
            else if (vv > v2) { v2 = vv; i2 = e; }
        }

        *reinterpret_cast<float2*>(&out_idx[2 * t]) = make_float2((float)i1, (float)i2);
        *reinterpret_cast<float2*>(&out_prob[2 * t]) = make_float2(p[i1] * inv, p[i2] * inv);
        atomicAdd(&lhist[i1], 1u);
        atomicAdd(&lhist[i2], 1u);
    }

    __syncthreads();
    if (tid < N_EXP) atomicAdd(&ghist[tid], lhist[tid]);   // integer -> deterministic
    __syncthreads();

    if (tid == 0) {
        __threadfence();                       // release ghist before ticket
        unsigned int old = atomicAdd(gdone, 1u);
        if (old == (unsigned int)(nblk - 1)) {
            const float denom = 1.0f / (float)(n_tokens * TOPK);
            float load[N_EXP], sum = 0.f;
#pragma unroll
            for (int e = 0; e < N_EXP; ++e) {
                unsigned int c = atomicAdd(&ghist[e], 0u);  // coherent read
                load[e] = (float)c * denom;
                sum += load[e];
            }
            const float mean = sum / (float)N_EXP;
            float var = 0.f;
#pragma unroll
            for (int e = 0; e < N_EXP; ++e) { float d = load[e] - mean; var += d * d; }
            var /= (float)N_EXP;
            const float cv_sq = var / (mean * mean + 1e-9f);
            out_aux[0] = 0.01f * cv_sq;
#pragma unroll
            for (int e = 0; e < N_EXP; ++e) out_load[e] = load[e];
        }
    }
}

extern "C" void kernel_launch(void* const* d_in, const int* in_sizes, int n_in,
                              void* d_out, int out_size, void* d_ws, size_t ws_size,
                              hipStream_t stream)
{
    const float* H = (const float*)d_in[0];
    const float* W = (const float*)d_in[1];
    const int n_tokens = in_sizes[0] / D_MODEL;  // 16384

    float* out = (float*)d_out;
    float* out_idx = out;
    float* out_prob = out + 2 * (size_t)n_tokens;
    float* out_aux = out + 4 * (size_t)n_tokens;
    float* out_load = out + 4 * (size_t)n_tokens + 1;

    // ws: part_ws [SPLIT * n_tokens * 8 floats] then ghist[8], gdone[1].
    float* part_ws = (float*)d_ws;
    const size_t part_bytes = (size_t)SPLIT * n_tokens * 8 * sizeof(float);  // 2 MB
    unsigned int* ghist = (unsigned int*)((char*)d_ws + part_bytes);
    unsigned int* gdone = ghist + N_EXP;

    hipMemsetAsync(ghist, 0, (N_EXP + 1) * sizeof(unsigned int), stream);

    const int nblk_t = (n_tokens + TPB - 1) / TPB;       // 256 token-groups
    hipLaunchKernelGGL(gate_partial_kernel, dim3(nblk_t * SPLIT), dim3(512), 0, stream,
                       H, W, part_ws, n_tokens);

    const int nblk_f = (n_tokens + 511) / 512;           // 32
    hipLaunchKernelGGL(token_finalize_kernel, dim3(nblk_f), dim3(512), 0, stream,
                       part_ws, ghist, gdone,
                       out_idx, out_prob, out_aux, out_load, n_tokens, nblk_f);
}

// Round 12
// 39.787 us; speedup vs baseline: 3.8501x; 1.0260x over previous
//
#include <hip/hip_runtime.h>

#define D_MODEL 2048
#define N_EXP 8
#define TOPK 2
#define TPB 64                // tokens per block
#define SPLIT 4               // k-split factor
#define KQ (D_MODEL / SPLIT)  // 512 floats per quarter
#define TILE 64               // floats per tile per row
#define NT (KQ / TILE)        // 8 tiles
#define TSTR 65               // transposed LDS stride: [k][token], +1 pad
#define OSTR 68               // overlay floats per token

// R9-exact gate (validated 32.9 us wall). Split-K4, transposed-LDS. Grid =
// 256 token-groups x 4 quarters = 1024 blocks -> 4 blocks/CU, 8 waves/SIMD.
// LDS tile TRANSPOSED [k][token] (+1 pad): staging scatter-writes and compute
// reads are conflict-free b32 patterns; compute reads share one address reg
// with offset immediates. W operands wave-uniform -> SGPR s_loads.
__global__ __launch_bounds__(512, 8) void gate_partial_kernel(
    const float* __restrict__ H, const float* __restrict__ W,
    float* __restrict__ part_ws, int n_tokens)
{
    __shared__ float lbuf[2][TILE][TSTR];   // 33280 B -> 4 blocks/CU

    const int tid = threadIdx.x;
    const int lane = tid & 63;
    const int w = tid >> 6;               // 0..7
    const int tb = blockIdx.x >> 2;
    const int q = blockIdx.x & 3;         // k-quarter
    const int t0 = tb * TPB;
    const int wc = __builtin_amdgcn_readfirstlane(w);

    // Staging coords: thread stages row srow, float4 slots scol and scol+8.
    const int srow = tid >> 3;            // 0..63 (token row)
    const int scol = tid & 7;
    const bool svalid = (t0 + srow) < n_tokens;
    const float4* hrow = reinterpret_cast<const float4*>(H)
                         + (size_t)(t0 + srow) * (D_MODEL / 4) + q * (KQ / 4);
    const float* Wq = W + q * KQ;         // expert stride D_MODEL
    const float4 fz = make_float4(0.f, 0.f, 0.f, 0.f);

    float acc[N_EXP];
#pragma unroll
    for (int e = 0; e < N_EXP; ++e) acc[e] = 0.f;

    // Prologue: stage tile 0 (transposed scatter: 4 b32 per float4).
    {
        float4 r0 = svalid ? hrow[scol] : fz;
        float4 r1 = svalid ? hrow[scol + 8] : fz;
        const float* p0 = reinterpret_cast<const float*>(&r0);
        const float* p1 = reinterpret_cast<const float*>(&r1);
#pragma unroll
        for (int jj = 0; jj < 4; ++jj) {
            lbuf[0][4 * scol + jj][srow] = p0[jj];
            lbuf[0][4 * (scol + 8) + jj][srow] = p1[jj];
        }
    }
    __syncthreads();

#pragma unroll
    for (int j = 0; j < NT; ++j) {
        const int b = j & 1;
        const bool pf = (j + 1 < NT);
        float4 r0 = fz, r1 = fz;
        if (pf && svalid) {               // issue next-tile loads early
            r0 = hrow[(j + 1) * 16 + scol];
            r1 = hrow[(j + 1) * 16 + scol + 8];
        }

        // Compute tile j: token = lane, k = wc*8 + i (conflict-free b32 reads).
        float x[8];
#pragma unroll
        for (int i = 0; i < 8; ++i) x[i] = lbuf[b][wc * 8 + i][lane];
#pragma unroll
        for (int e = 0; e < N_EXP; ++e) {
            float a = acc[e];
#pragma unroll
            for (int i = 0; i < 8; ++i)
                a = fmaf(x[i], Wq[e * D_MODEL + j * TILE + wc * 8 + i], a);  // scalar
            acc[e] = a;
        }

        if (pf) {
            const float* p0 = reinterpret_cast<const float*>(&r0);
            const float* p1 = reinterpret_cast<const float*>(&r1);
#pragma unroll
            for (int jj = 0; jj < 4; ++jj) {
                lbuf[b ^ 1][4 * scol + jj][srow] = p0[jj];
                lbuf[b ^ 1][4 * (scol + 8) + jj][srow] = p1[jj];
            }
        }
        __syncthreads();
    }

    // Partials -> LDS overlay (overlay region is free after the last barrier).
    float* part = &lbuf[0][0][0];
    {
        float* dst = part + lane * OSTR + wc * 8;
        *reinterpret_cast<float4*>(dst) = make_float4(acc[0], acc[1], acc[2], acc[3]);
        *reinterpret_cast<float4*>(dst + 4) = make_float4(acc[4], acc[5], acc[6], acc[7]);
    }
    __syncthreads();

    // Wave 0: fixed-order 8-chunk sum -> 8 quarter-logits -> part_ws[q][t][e].
    if (w == 0 && (t0 + lane) < n_tokens) {
        const float* src = part + lane * OSTR;
        float4 s0 = *reinterpret_cast<const float4*>(src);
        float4 s1 = *reinterpret_cast<const float4*>(src + 4);
        float lg[N_EXP] = {s0.x, s0.y, s0.z, s0.w, s1.x, s1.y, s1.z, s1.w};
#pragma unroll
        for (int c = 1; c < 8; ++c) {
            float4 c0 = *reinterpret_cast<const float4*>(src + c * 8);
            float4 c1 = *reinterpret_cast<const float4*>(src + c * 8 + 4);
            lg[0] += c0.x; lg[1] += c0.y; lg[2] += c0.z; lg[3] += c0.w;
            lg[4] += c1.x; lg[5] += c1.y; lg[6] += c1.z; lg[7] += c1.w;
        }
        float* dst = part_ws + ((size_t)q * n_tokens + (t0 + lane)) * 8;
        *reinterpret_cast<float4*>(dst) = make_float4(lg[0], lg[1], lg[2], lg[3]);
        *reinterpret_cast<float4*>(dst + 4) = make_float4(lg[4], lg[5], lg[6], lg[7]);
    }
}

// Merged tail (the ONE change vs R9): one thread per token, 32 blocks x 512.
// Fixed-order quarter sum, softmax, top-2, outputs; per-block hist -> ghist
// device-scope atomics; gdone ticket (atomics are drained by the barrier's
// vmcnt(0) before the ticket -> no fence needed); last block computes aux/load.
__global__ __launch_bounds__(512) void token_finalize_kernel(
    const float* __restrict__ part_ws,
    unsigned int* __restrict__ ghist, unsigned int* __restrict__ gdone,
    float* __restrict__ out_idx, float* __restrict__ out_prob,
    float* __restrict__ out_aux, float* __restrict__ out_load,
    int n_tokens, int nblk)
{
    __shared__ unsigned int lhist[N_EXP];
    const int tid = threadIdx.x;
    if (tid < N_EXP) lhist[tid] = 0u;
    __syncthreads();

    const int t = blockIdx.x * 512 + tid;
    if (t < n_tokens) {
        float lg[N_EXP] = {0.f, 0.f, 0.f, 0.f, 0.f, 0.f, 0.f, 0.f};
#pragma unroll
        for (int qq = 0; qq < SPLIT; ++qq) {   // fixed order -> deterministic
            const float4* src = reinterpret_cast<const float4*>(
                part_ws + ((size_t)qq * n_tokens + t) * 8);
            const float4 a0 = src[0], a1 = src[1];
            lg[0] += a0.x; lg[1] += a0.y; lg[2] += a0.z; lg[3] += a0.w;
            lg[4] += a1.x; lg[5] += a1.y; lg[6] += a1.z; lg[7] += a1.w;
        }

        float m = lg[0];
#pragma unroll
        for (int e = 1; e < N_EXP; ++e) m = fmaxf(m, lg[e]);
        float p[N_EXP], s = 0.f;
#pragma unroll
        for (int e = 0; e < N_EXP; ++e) { p[e] = expf(lg[e] - m); s += p[e]; }
        const float inv = 1.f / s;

        float v1 = -INFINITY, v2 = -INFINITY;
        int i1 = 0, i2 = 0;
#pragma unroll
        for (int e = 0; e < N_EXP; ++e) {
            float vv = lg[e];
            if (vv > v1) { v2 = v1; i2 = i1; v1 = vv; i1 = e; }
            else if (vv > v2) { v2 = vv; i2 = e; }
        }

        *reinterpret_cast<float2*>(&out_idx[2 * t]) = make_float2((float)i1, (float)i2);
        *reinterpret_cast<float2*>(&out_prob[2 * t]) = make_float2(p[i1] * inv, p[i2] * inv);
        atomicAdd(&lhist[i1], 1u);
        atomicAdd(&lhist[i2], 1u);
    }

    __syncthreads();
    if (tid < N_EXP) atomicAdd(&ghist[tid], lhist[tid]);   // device-scope, coherent
    __syncthreads();   // vmcnt(0) drain: ghist adds globally visible before ticket

    if (tid == 0) {
        unsigned int old = atomicAdd(gdone, 1u);
        if (old == (unsigned int)(nblk - 1)) {
            const float denom = 1.0f / (float)(n_tokens * TOPK);
            float load[N_EXP], sum = 0.f;
#pragma unroll
            for (int e = 0; e < N_EXP; ++e) {
                unsigned int c = atomicAdd(&ghist[e], 0u);  // coherent read
                load[e] = (float)c * denom;
                sum += load[e];
            }
            const float mean = sum / (float)N_EXP;
            float var = 0.f;
#pragma unroll
            for (int e = 0; e < N_EXP; ++e) { float d = load[e] - mean; var += d * d; }
            var /= (float)N_EXP;
            const float cv_sq = var / (mean * mean + 1e-9f);
            out_aux[0] = 0.01f * cv_sq;
#pragma unroll
            for (int e = 0; e < N_EXP; ++e) out_load[e] = load[e];
        }
    }
}

extern "C" void kernel_launch(void* const* d_in, const int* in_sizes, int n_in,
                              void* d_out, int out_size, void* d_ws, size_t ws_size,
                              hipStream_t stream)
{
    const float* H = (const float*)d_in[0];
    const float* W = (const float*)d_in[1];
    const int n_tokens = in_sizes[0] / D_MODEL;  // 16384

    float* out = (float*)d_out;
    float* out_idx = out;
    float* out_prob = out + 2 * (size_t)n_tokens;
    float* out_aux = out + 4 * (size_t)n_tokens;
    float* out_load = out + 4 * (size_t)n_tokens + 1;

    // ws: part_ws [SPLIT * n_tokens * 8 floats] then ghist[8], gdone[1].
    float* part_ws = (float*)d_ws;
    const size_t part_bytes = (size_t)SPLIT * n_tokens * 8 * sizeof(float);  // 2 MB
    unsigned int* ghist = (unsigned int*)((char*)d_ws + part_bytes);
    unsigned int* gdone = ghist + N_EXP;

    hipMemsetAsync(ghist, 0, (N_EXP + 1) * sizeof(unsigned int), stream);

    const int nblk_t = (n_tokens + TPB - 1) / TPB;       // 256 token-groups
    hipLaunchKernelGGL(gate_partial_kernel, dim3(nblk_t * SPLIT), dim3(512), 0, stream,
                       H, W, part_ws, n_tokens);

    const int nblk_f = (n_tokens + 511) / 512;           // 32
    hipLaunchKernelGGL(token_finalize_kernel, dim3(nblk_f), dim3(512), 0, stream,
                       part_ws, ghist, gdone,
                       out_idx, out_prob, out_aux, out_load, n_tokens, nblk_f);
}

// Round 13
// 32.253 us; speedup vs baseline: 4.7493x; 1.2336x over previous
//
#include <hip/hip_runtime.h>

#define D_MODEL 2048
#define N_EXP 8
#define TOPK 2
#define TPB 64                // tokens per block
#define SPLIT 4               // k-split factor
#define KQ (D_MODEL / SPLIT)  // 512 floats per quarter
#define TILE 64               // floats per tile per row
#define NT (KQ / TILE)        // 8 tiles
#define TSTR 65               // transposed LDS stride: [k][token], +1 pad
#define OSTR 68               // overlay floats per token

// R9-exact gate + in-kernel semaphore zeroing (replaces the hipMemsetAsync
// whose 36-byte fill dispatch cost ~7 us wall in R11). Block (tb=0,q=0)
// zeroes ghist/gdone with plain stores at kernel start; the tail kernel only
// launches after the whole gate kernel completes, so visibility is guaranteed
// by the kernel boundary. Everything else unchanged from the validated R9.
__global__ __launch_bounds__(512, 8) void gate_partial_kernel(
    const float* __restrict__ H, const float* __restrict__ W,
    float* __restrict__ part_ws, unsigned int* __restrict__ ghist,
    int n_tokens)
{
    __shared__ float lbuf[2][TILE][TSTR];   // 33280 B -> 4 blocks/CU

    const int tid = threadIdx.x;
    const int lane = tid & 63;
    const int w = tid >> 6;               // 0..7
    const int tb = blockIdx.x >> 2;
    const int q = blockIdx.x & 3;         // k-quarter
    const int t0 = tb * TPB;
    const int wc = __builtin_amdgcn_readfirstlane(w);

    // Zero ghist[0..7] + gdone (9 words) once per launch.
    if (blockIdx.x == 0 && tid < N_EXP + 1) ghist[tid] = 0u;

    // Staging coords: thread stages row srow, float4 slots scol and scol+8.
    const int srow = tid >> 3;            // 0..63 (token row)
    const int scol = tid & 7;
    const bool svalid = (t0 + srow) < n_tokens;
    const float4* hrow = reinterpret_cast<const float4*>(H)
                         + (size_t)(t0 + srow) * (D_MODEL / 4) + q * (KQ / 4);
    const float* Wq = W + q * KQ;         // expert stride D_MODEL
    const float4 fz = make_float4(0.f, 0.f, 0.f, 0.f);

    float acc[N_EXP];
#pragma unroll
    for (int e = 0; e < N_EXP; ++e) acc[e] = 0.f;

    // Prologue: stage tile 0 (transposed scatter: 4 b32 per float4).
    {
        float4 r0 = svalid ? hrow[scol] : fz;
        float4 r1 = svalid ? hrow[scol + 8] : fz;
        const float* p0 = reinterpret_cast<const float*>(&r0);
        const float* p1 = reinterpret_cast<const float*>(&r1);
#pragma unroll
        for (int jj = 0; jj < 4; ++jj) {
            lbuf[0][4 * scol + jj][srow] = p0[jj];
            lbuf[0][4 * (scol + 8) + jj][srow] = p1[jj];
        }
    }
    __syncthreads();

#pragma unroll
    for (int j = 0; j < NT; ++j) {
        const int b = j & 1;
        const bool pf = (j + 1 < NT);
        float4 r0 = fz, r1 = fz;
        if (pf && svalid) {               // issue next-tile loads early
            r0 = hrow[(j + 1) * 16 + scol];
            r1 = hrow[(j + 1) * 16 + scol + 8];
        }

        // Compute tile j: token = lane, k = wc*8 + i (conflict-free b32 reads).
        float x[8];
#pragma unroll
        for (int i = 0; i < 8; ++i) x[i] = lbuf[b][wc * 8 + i][lane];
#pragma unroll
        for (int e = 0; e < N_EXP; ++e) {
            float a = acc[e];
#pragma unroll
            for (int i = 0; i < 8; ++i)
                a = fmaf(x[i], Wq[e * D_MODEL + j * TILE + wc * 8 + i], a);  // scalar
            acc[e] = a;
        }

        if (pf) {
            const float* p0 = reinterpret_cast<const float*>(&r0);
            const float* p1 = reinterpret_cast<const float*>(&r1);
#pragma unroll
            for (int jj = 0; jj < 4; ++jj) {
                lbuf[b ^ 1][4 * scol + jj][srow] = p0[jj];
                lbuf[b ^ 1][4 * (scol + 8) + jj][srow] = p1[jj];
            }
        }
        __syncthreads();
    }

    // Partials -> LDS overlay (overlay region is free after the last barrier).
    float* part = &lbuf[0][0][0];
    {
        float* dst = part + lane * OSTR + wc * 8;
        *reinterpret_cast<float4*>(dst) = make_float4(acc[0], acc[1], acc[2], acc[3]);
        *reinterpret_cast<float4*>(dst + 4) = make_float4(acc[4], acc[5], acc[6], acc[7]);
    }
    __syncthreads();

    // Wave 0: fixed-order 8-chunk sum -> 8 quarter-logits -> part_ws[q][t][e].
    if (w == 0 && (t0 + lane) < n_tokens) {
        const float* src = part + lane * OSTR;
        float4 s0 = *reinterpret_cast<const float4*>(src);
        float4 s1 = *reinterpret_cast<const float4*>(src + 4);
        float lg[N_EXP] = {s0.x, s0.y, s0.z, s0.w, s1.x, s1.y, s1.z, s1.w};
#pragma unroll
        for (int c = 1; c < 8; ++c) {
            float4 c0 = *reinterpret_cast<const float4*>(src + c * 8);
            float4 c1 = *reinterpret_cast<const float4*>(src + c * 8 + 4);
            lg[0] += c0.x; lg[1] += c0.y; lg[2] += c0.z; lg[3] += c0.w;
            lg[4] += c1.x; lg[5] += c1.y; lg[6] += c1.z; lg[7] += c1.w;
        }
        float* dst = part_ws + ((size_t)q * n_tokens + (t0 + lane)) * 8;
        *reinterpret_cast<float4*>(dst) = make_float4(lg[0], lg[1], lg[2], lg[3]);
        *reinterpret_cast<float4*>(dst + 4) = make_float4(lg[4], lg[5], lg[6], lg[7]);
    }
}

// Merged tail: one thread per token, 32 blocks x 512. Fixed-order quarter sum,
// softmax, top-2, outputs; per-block hist -> ghist device-scope atomics; gdone
// ticket; last block computes aux/load from ghist (integer counts -> exact).
__global__ __launch_bounds__(512) void token_finalize_kernel(
    const float* __restrict__ part_ws,
    unsigned int* __restrict__ ghist, unsigned int* __restrict__ gdone,
    float* __restrict__ out_idx, float* __restrict__ out_prob,
    float* __restrict__ out_aux, float* __restrict__ out_load,
    int n_tokens, int nblk)
{
    __shared__ unsigned int lhist[N_EXP];
    const int tid = threadIdx.x;
    if (tid < N_EXP) lhist[tid] = 0u;
    __syncthreads();

    const int t = blockIdx.x * 512 + tid;
    if (t < n_tokens) {
        float lg[N_EXP] = {0.f, 0.f, 0.f, 0.f, 0.f, 0.f, 0.f, 0.f};
#pragma unroll
        for (int qq = 0; qq < SPLIT; ++qq) {   // fixed order -> deterministic
            const float4* src = reinterpret_cast<const float4*>(
                part_ws + ((size_t)qq * n_tokens + t) * 8);
            const float4 a0 = src[0], a1 = src[1];
            lg[0] += a0.x; lg[1] += a0.y; lg[2] += a0.z; lg[3] += a0.w;
            lg[4] += a1.x; lg[5] += a1.y; lg[6] += a1.z; lg[7] += a1.w;
        }

        float m = lg[0];
#pragma unroll
        for (int e = 1; e < N_EXP; ++e) m = fmaxf(m, lg[e]);
        float p[N_EXP], s = 0.f;
#pragma unroll
        for (int e = 0; e < N_EXP; ++e) { p[e] = expf(lg[e] - m); s += p[e]; }
        const float inv = 1.f / s;

        float v1 = -INFINITY, v2 = -INFINITY;
        int i1 = 0, i2 = 0;
#pragma unroll
        for (int e = 0; e < N_EXP; ++e) {
            float vv = lg[e];
            if (vv > v1) { v2 = v1; i2 = i1; v1 = vv; i1 = e; }
            else if (vv > v2) { v2 = vv; i2 = e; }
        }

        *reinterpret_cast<float2*>(&out_idx[2 * t]) = make_float2((float)i1, (float)i2);
        *reinterpret_cast<float2*>(&out_prob[2 * t]) = make_float2(p[i1] * inv, p[i2] * inv);
        atomicAdd(&lhist[i1], 1u);
        atomicAdd(&lhist[i2], 1u);
    }

    __syncthreads();
    if (tid < N_EXP) atomicAdd(&ghist[tid], lhist[tid]);   // device-scope, coherent
    __syncthreads();   // drains the ghist atomics before the ticket

    if (tid == 0) {
        unsigned int old = atomicAdd(gdone, 1u);
        if (old == (unsigned int)(nblk - 1)) {
            const float denom = 1.0f / (float)(n_tokens * TOPK);
            float load[N_EXP], sum = 0.f;
#pragma unroll
            for (int e = 0; e < N_EXP; ++e) {
                unsigned int c = atomicAdd(&ghist[e], 0u);  // coherent read
                load[e] = (float)c * denom;
                sum += load[e];
            }
            const float mean = sum / (float)N_EXP;
            float var = 0.f;
#pragma unroll
            for (int e = 0; e < N_EXP; ++e) { float d = load[e] - mean; var += d * d; }
            var /= (float)N_EXP;
            const float cv_sq = var / (mean * mean + 1e-9f);
            out_aux[0] = 0.01f * cv_sq;
#pragma unroll
            for (int e = 0; e < N_EXP; ++e) out_load[e] = load[e];
        }
    }
}

extern "C" void kernel_launch(void* const* d_in, const int* in_sizes, int n_in,
                              void* d_out, int out_size, void* d_ws, size_t ws_size,
                              hipStream_t stream)
{
    const float* H = (const float*)d_in[0];
    const float* W = (const float*)d_in[1];
    const int n_tokens = in_sizes[0] / D_MODEL;  // 16384

    float* out = (float*)d_out;
    float* out_idx = out;
    float* out_prob = out + 2 * (size_t)n_tokens;
    float* out_aux = out + 4 * (size_t)n_tokens;
    float* out_load = out + 4 * (size_t)n_tokens + 1;

    // ws: part_ws [SPLIT * n_tokens * 8 floats] then ghist[8], gdone[1].
    float* part_ws = (float*)d_ws;
    const size_t part_bytes = (size_t)SPLIT * n_tokens * 8 * sizeof(float);  // 2 MB
    unsigned int* ghist = (unsigned int*)((char*)d_ws + part_bytes);
    unsigned int* gdone = ghist + N_EXP;

    const int nblk_t = (n_tokens + TPB - 1) / TPB;       // 256 token-groups
    hipLaunchKernelGGL(gate_partial_kernel, dim3(nblk_t * SPLIT), dim3(512), 0, stream,
                       H, W, part_ws, ghist, n_tokens);

    const int nblk_f = (n_tokens + 511) / 512;           // 32
    hipLaunchKernelGGL(token_finalize_kernel, dim3(nblk_f), dim3(512), 0, stream,
                       part_ws, ghist, gdone,
                       out_idx, out_prob, out_aux, out_load, n_tokens, nblk_f);
}

// Round 14
// 31.953 us; speedup vs baseline: 4.7939x; 1.0094x over previous
//
#include <hip/hip_runtime.h>

#define D_MODEL 2048
#define N_EXP 8
#define TOPK 2
#define TPB 64                // tokens per block
#define SPLIT 8               // k-split factor (R12 had 4) -> 2048 blocks, 2 rounds
#define KQ (D_MODEL / SPLIT)  // 256 floats per slice
#define TILE 64               // floats per tile per row
#define NT (KQ / TILE)        // 4 tiles
#define TSTR 65               // transposed LDS stride: [k][token], +1 pad
#define OSTR 68               // overlay floats per token

// R12 gate with SPLIT=8: grid = 256 token-groups x 8 k-slices = 2048 blocks at
// 4 blocks/CU -> TWO co-residency rounds. Round-2 blocks backfill as round-1
// blocks finish, so prologue loads and barrier drains overlap other blocks'
// compute (breaks the all-blocks-lockstep of the exactly-resident grid).
// Everything else byte-identical to the validated R12 structure.
__global__ __launch_bounds__(512, 8) void gate_partial_kernel(
    const float* __restrict__ H, const float* __restrict__ W,
    float* __restrict__ part_ws, unsigned int* __restrict__ ghist,
    int n_tokens)
{
    __shared__ float lbuf[2][TILE][TSTR];   // 33280 B -> 4 blocks/CU

    const int tid = threadIdx.x;
    const int lane = tid & 63;
    const int w = tid >> 6;               // 0..7
    const int tb = blockIdx.x >> 3;
    const int q = blockIdx.x & 7;         // k-slice
    const int t0 = tb * TPB;
    const int wc = __builtin_amdgcn_readfirstlane(w);

    // Zero ghist[0..7] + gdone (9 words) once per launch.
    if (blockIdx.x == 0 && tid < N_EXP + 1) ghist[tid] = 0u;

    // Staging coords: thread stages row srow, float4 slots scol and scol+8.
    const int srow = tid >> 3;            // 0..63 (token row)
    const int scol = tid & 7;
    const bool svalid = (t0 + srow) < n_tokens;
    const float4* hrow = reinterpret_cast<const float4*>(H)
                         + (size_t)(t0 + srow) * (D_MODEL / 4) + q * (KQ / 4);
    const float* Wq = W + q * KQ;         // expert stride D_MODEL
    const float4 fz = make_float4(0.f, 0.f, 0.f, 0.f);

    float acc[N_EXP];
#pragma unroll
    for (int e = 0; e < N_EXP; ++e) acc[e] = 0.f;

    // Prologue: stage tile 0 (transposed scatter: 4 b32 per float4).
    {
        float4 r0 = svalid ? hrow[scol] : fz;
        float4 r1 = svalid ? hrow[scol + 8] : fz;
        const float* p0 = reinterpret_cast<const float*>(&r0);
        const float* p1 = reinterpret_cast<const float*>(&r1);
#pragma unroll
        for (int jj = 0; jj < 4; ++jj) {
            lbuf[0][4 * scol + jj][srow] = p0[jj];
            lbuf[0][4 * (scol + 8) + jj][srow] = p1[jj];
        }
    }
    __syncthreads();

#pragma unroll
    for (int j = 0; j < NT; ++j) {
        const int b = j & 1;
        const bool pf = (j + 1 < NT);
        float4 r0 = fz, r1 = fz;
        if (pf && svalid) {               // issue next-tile loads early
            r0 = hrow[(j + 1) * 16 + scol];
            r1 = hrow[(j + 1) * 16 + scol + 8];
        }

        // Compute tile j: token = lane, k = wc*8 + i (conflict-free b32 reads).
        float x[8];
#pragma unroll
        for (int i = 0; i < 8; ++i) x[i] = lbuf[b][wc * 8 + i][lane];
#pragma unroll
        for (int e = 0; e < N_EXP; ++e) {
            float a = acc[e];
#pragma unroll
            for (int i = 0; i < 8; ++i)
                a = fmaf(x[i], Wq[e * D_MODEL + j * TILE + wc * 8 + i], a);  // scalar
            acc[e] = a;
        }

        if (pf) {
            const float* p0 = reinterpret_cast<const float*>(&r0);
            const float* p1 = reinterpret_cast<const float*>(&r1);
#pragma unroll
            for (int jj = 0; jj < 4; ++jj) {
                lbuf[b ^ 1][4 * scol + jj][srow] = p0[jj];
                lbuf[b ^ 1][4 * (scol + 8) + jj][srow] = p1[jj];
            }
        }
        __syncthreads();
    }

    // Partials -> LDS overlay (overlay region is free after the last barrier).
    float* part = &lbuf[0][0][0];
    {
        float* dst = part + lane * OSTR + wc * 8;
        *reinterpret_cast<float4*>(dst) = make_float4(acc[0], acc[1], acc[2], acc[3]);
        *reinterpret_cast<float4*>(dst + 4) = make_float4(acc[4], acc[5], acc[6], acc[7]);
    }
    __syncthreads();

    // Wave 0: fixed-order 8-chunk sum -> 8 slice-logits -> part_ws[q][t][e].
    if (w == 0 && (t0 + lane) < n_tokens) {
        const float* src = part + lane * OSTR;
        float4 s0 = *reinterpret_cast<const float4*>(src);
        float4 s1 = *reinterpret_cast<const float4*>(src + 4);
        float lg[N_EXP] = {s0.x, s0.y, s0.z, s0.w, s1.x, s1.y, s1.z, s1.w};
#pragma unroll
        for (int c = 1; c < 8; ++c) {
            float4 c0 = *reinterpret_cast<const float4*>(src + c * 8);
            float4 c1 = *reinterpret_cast<const float4*>(src + c * 8 + 4);
            lg[0] += c0.x; lg[1] += c0.y; lg[2] += c0.z; lg[3] += c0.w;
            lg[4] += c1.x; lg[5] += c1.y; lg[6] += c1.z; lg[7] += c1.w;
        }
        float* dst = part_ws + ((size_t)q * n_tokens + (t0 + lane)) * 8;
        *reinterpret_cast<float4*>(dst) = make_float4(lg[0], lg[1], lg[2], lg[3]);
        *reinterpret_cast<float4*>(dst + 4) = make_float4(lg[4], lg[5], lg[6], lg[7]);
    }
}

// Merged tail: one thread per token, 32 blocks x 512. Fixed-order slice sum,
// softmax, top-2, outputs; per-block hist -> ghist device-scope atomics; gdone
// ticket; last block computes aux/load from ghist (integer counts -> exact).
__global__ __launch_bounds__(512) void token_finalize_kernel(
    const float* __restrict__ part_ws,
    unsigned int* __restrict__ ghist, unsigned int* __restrict__ gdone,
    float* __restrict__ out_idx, float* __restrict__ out_prob,
    float* __restrict__ out_aux, float* __restrict__ out_load,
    int n_tokens, int nblk)
{
    __shared__ unsigned int lhist[N_EXP];
    const int tid = threadIdx.x;
    if (tid < N_EXP) lhist[tid] = 0u;
    __syncthreads();

    const int t = blockIdx.x * 512 + tid;
    if (t < n_tokens) {
        float lg[N_EXP] = {0.f, 0.f, 0.f, 0.f, 0.f, 0.f, 0.f, 0.f};
#pragma unroll
        for (int qq = 0; qq < SPLIT; ++qq) {   // fixed order -> deterministic
            const float4* src = reinterpret_cast<const float4*>(
                part_ws + ((size_t)qq * n_tokens + t) * 8);
            const float4 a0 = src[0], a1 = src[1];
            lg[0] += a0.x; lg[1] += a0.y; lg[2] += a0.z; lg[3] += a0.w;
            lg[4] += a1.x; lg[5] += a1.y; lg[6] += a1.z; lg[7] += a1.w;
        }

        float m = lg[0];
#pragma unroll
        for (int e = 1; e < N_EXP; ++e) m = fmaxf(m, lg[e]);
        float p[N_EXP], s = 0.f;
#pragma unroll
        for (int e = 0; e < N_EXP; ++e) { p[e] = expf(lg[e] - m); s += p[e]; }
        const float inv = 1.f / s;

        float v1 = -INFINITY, v2 = -INFINITY;
        int i1 = 0, i2 = 0;
#pragma unroll
        for (int e = 0; e < N_EXP; ++e) {
            float vv = lg[e];
            if (vv > v1) { v2 = v1; i2 = i1; v1 = vv; i1 = e; }
            else if (vv > v2) { v2 = vv; i2 = e; }
        }

        *reinterpret_cast<float2*>(&out_idx[2 * t]) = make_float2((float)i1, (float)i2);
        *reinterpret_cast<float2*>(&out_prob[2 * t]) = make_float2(p[i1] * inv, p[i2] * inv);
        atomicAdd(&lhist[i1], 1u);
        atomicAdd(&lhist[i2], 1u);
    }

    __syncthreads();
    if (tid < N_EXP) atomicAdd(&ghist[tid], lhist[tid]);   // device-scope, coherent
    __syncthreads();   // drains the ghist atomics before the ticket

    if (tid == 0) {
        unsigned int old = atomicAdd(gdone, 1u);
        if (old == (unsigned int)(nblk - 1)) {
            const float denom = 1.0f / (float)(n_tokens * TOPK);
            float load[N_EXP], sum = 0.f;
#pragma unroll
            for (int e = 0; e < N_EXP; ++e) {
                unsigned int c = atomicAdd(&ghist[e], 0u);  // coherent read
                load[e] = (float)c * denom;
                sum += load[e];
            }
            const float mean = sum / (float)N_EXP;
            float var = 0.f;
#pragma unroll
            for (int e = 0; e < N_EXP; ++e) { float d = load[e] - mean; var += d * d; }
            var /= (float)N_EXP;
            const float cv_sq = var / (mean * mean + 1e-9f);
            out_aux[0] = 0.01f * cv_sq;
#pragma unroll
            for (int e = 0; e < N_EXP; ++e) out_load[e] = load[e];
        }
    }
}

extern "C" void kernel_launch(void* const* d_in, const int* in_sizes, int n_in,
                              void* d_out, int out_size, void* d_ws, size_t ws_size,
                              hipStream_t stream)
{
    const float* H = (const float*)d_in[0];
    const float* W = (const float*)d_in[1];
    const int n_tokens = in_sizes[0] / D_MODEL;  // 16384

    float* out = (float*)d_out;
    float* out_idx = out;
    float* out_prob = out + 2 * (size_t)n_tokens;
    float* out_aux = out + 4 * (size_t)n_tokens;
    float* out_load = out + 4 * (size_t)n_tokens + 1;

    // ws: part_ws [SPLIT * n_tokens * 8 floats] then ghist[8], gdone[1].
    float* part_ws = (float*)d_ws;
    const size_t part_bytes = (size_t)SPLIT * n_tokens * 8 * sizeof(float);  // 4 MB
    unsigned int* ghist = (unsigned int*)((char*)d_ws + part_bytes);
    unsigned int* gdone = ghist + N_EXP;

    const int nblk_t = (n_tokens + TPB - 1) / TPB;       // 256 token-groups
    hipLaunchKernelGGL(gate_partial_kernel, dim3(nblk_t * SPLIT), dim3(512), 0, stream,
                       H, W, part_ws, ghist, n_tokens);

    const int nblk_f = (n_tokens + 511) / 512;           // 32
    hipLaunchKernelGGL(token_finalize_kernel, dim3(nblk_f), dim3(512), 0, stream,
                       part_ws, ghist, gdone,
                       out_idx, out_prob, out_aux, out_load, n_tokens, nblk_f);
}